// Round 5
// baseline (638.336 us; speedup 1.0000x reference)
//
#include <hip/hip_runtime.h>
#include <hip/hip_bf16.h>

// SimpleGraphConv (RGCN-mean), fused aggregate-first, edge-parallel:
//   out[n] = bias + sum_r ( mean_{e: dst=n, type=r} x[src[e]] ) @ W[r]
//
//   1. counting sort edges by key = rel*N + dst -> CSR; epack[pos] = (dst<<32)|src
//   2. fused kernel, per 64-node tile, per relation:
//      - tile's edge range = off[key0]..off[key0+64]  (uniform! keys contiguous)
//      - edge-parallel: 16-lane groups stripe edges, ds_add_f32 into swizzled
//        f32 LDS tile (no stragglers, no per-key latency chains)
//      - normalize straight into bf16 MFMA A-fragments in registers
//      - W staged async via global_load_lds (pre-swizzled global layout)
//      - acc held across relations; out written once

#define C128 128
#define BR 64

typedef __attribute__((ext_vector_type(8))) short short8;
typedef __attribute__((ext_vector_type(4))) unsigned short ushort4v;
typedef __attribute__((ext_vector_type(4))) float f32x4;
typedef unsigned long long u64;

__device__ __forceinline__ void gload_lds16(void* lds, const void* gsrc) {
    __builtin_amdgcn_global_load_lds(
        (const __attribute__((address_space(1))) unsigned int*)gsrc,
        (__attribute__((address_space(3))) unsigned int*)lds, 16, 0, 0);
}

__device__ __forceinline__ float bf16_bits_to_f32(unsigned short u) {
    union { unsigned int i; float f; } c;
    c.i = ((unsigned int)u) << 16;
    return c.f;
}

// ------- merged: hist | wconv | xconv (independent work, block-split) -------

__global__ __launch_bounds__(256) void pre_kernel(const int* __restrict__ ei,
                                                  const int* __restrict__ et,
                                                  unsigned* __restrict__ cursor,
                                                  const float* __restrict__ W,
                                                  __hip_bfloat16* __restrict__ WbT,
                                                  const float* __restrict__ x,
                                                  __hip_bfloat16* __restrict__ xb,
                                                  int n_edges, int n_nodes,
                                                  int hblk, int wblk, int wtot, int xt8) {
    int bid = blockIdx.x;
    if (bid < hblk) {
        int e = bid * 256 + threadIdx.x;
        if (e < n_edges)
            atomicAdd(&cursor[(size_t)et[e] * n_nodes + ei[n_edges + e]], 1u);
    } else if (bid < hblk + wblk) {
        int i = (bid - hblk) * 256 + threadIdx.x;
        if (i < wtot) {
            int r = i >> 14, k = (i >> 7) & 127, n = i & 127;
            int pos = (r << 14) + (n << 7) + ((((k >> 3) ^ (n & 7)) << 3) | (k & 7));
            WbT[pos] = __float2bfloat16(W[i]);
        }
    } else {
        int i = (bid - hblk - wblk) * 256 + threadIdx.x;
        if (i < xt8) {
            const float4* src = reinterpret_cast<const float4*>(x + (size_t)i * 8);
            float4 v0 = src[0], v1 = src[1];
            short8 o;
            o[0] = (short)__bfloat16_as_ushort(__float2bfloat16(v0.x));
            o[1] = (short)__bfloat16_as_ushort(__float2bfloat16(v0.y));
            o[2] = (short)__bfloat16_as_ushort(__float2bfloat16(v0.z));
            o[3] = (short)__bfloat16_as_ushort(__float2bfloat16(v0.w));
            o[4] = (short)__bfloat16_as_ushort(__float2bfloat16(v1.x));
            o[5] = (short)__bfloat16_as_ushort(__float2bfloat16(v1.y));
            o[6] = (short)__bfloat16_as_ushort(__float2bfloat16(v1.z));
            o[7] = (short)__bfloat16_as_ushort(__float2bfloat16(v1.w));
            *reinterpret_cast<short8*>(reinterpret_cast<unsigned short*>(xb) + (size_t)i * 8) = o;
        }
    }
}

// ---------------- scan (3-kernel) ----------------

__global__ __launch_bounds__(256) void scan1_kernel(const unsigned* __restrict__ cnt,
                                                    unsigned* __restrict__ part, int total) {
    __shared__ unsigned s[256];
    int t = threadIdx.x;
    int base = blockIdx.x * 1024 + t * 4;
    unsigned sum = 0;
#pragma unroll
    for (int i = 0; i < 4; ++i) {
        int idx = base + i;
        if (idx < total) sum += cnt[idx];
    }
    s[t] = sum;
    __syncthreads();
    for (int d = 128; d > 0; d >>= 1) {
        if (t < d) s[t] += s[t + d];
        __syncthreads();
    }
    if (t == 0) part[blockIdx.x] = s[0];
}

__global__ __launch_bounds__(512) void scan2_kernel(unsigned* __restrict__ part, int nblk) {
    __shared__ unsigned s[512];
    int t = threadIdx.x;
    unsigned run = 0;
    for (int base = 0; base < nblk; base += 512) {
        int i = base + t;
        unsigned v = (i < nblk) ? part[i] : 0u;
        s[t] = v;
        __syncthreads();
        for (int d = 1; d < 512; d <<= 1) {
            unsigned u = (t >= d) ? s[t - d] : 0u;
            __syncthreads();
            s[t] += u;
            __syncthreads();
        }
        unsigned incl = s[t];
        if (i < nblk) part[i] = run + incl - v;  // exclusive
        unsigned tot = s[511];
        __syncthreads();
        run += tot;
    }
}

__global__ __launch_bounds__(256) void scan3_kernel(unsigned* __restrict__ cursor,
                                                    unsigned* __restrict__ off,
                                                    const unsigned* __restrict__ part,
                                                    int total, int n_edges) {
    __shared__ unsigned s[256];
    int t = threadIdx.x;
    int base = blockIdx.x * 1024 + t * 4;
    unsigned v[4];
    unsigned tsum = 0;
#pragma unroll
    for (int i = 0; i < 4; ++i) {
        int idx = base + i;
        v[i] = (idx < total) ? cursor[idx] : 0u;
        tsum += v[i];
    }
    s[t] = tsum;
    __syncthreads();
    for (int d = 1; d < 256; d <<= 1) {
        unsigned u = (t >= d) ? s[t - d] : 0u;
        __syncthreads();
        s[t] += u;
        __syncthreads();
    }
    unsigned run = s[t] - tsum + part[blockIdx.x];
#pragma unroll
    for (int i = 0; i < 4; ++i) {
        int idx = base + i;
        if (idx < total) {
            off[idx] = run;
            cursor[idx] = run;
            run += v[i];
        }
    }
    if (blockIdx.x == 0 && t == 0) off[total] = (unsigned)n_edges;
}

__global__ __launch_bounds__(256) void place_kernel(const int* __restrict__ ei,
                                                    const int* __restrict__ et,
                                                    unsigned* __restrict__ cursor,
                                                    u64* __restrict__ epack,
                                                    int n_edges, int n_nodes) {
    int e = blockIdx.x * 256 + threadIdx.x;
    if (e < n_edges) {
        int src = ei[e];
        int dst = ei[n_edges + e];
        int key = et[e] * n_nodes + dst;
        unsigned pos = atomicAdd(&cursor[key], 1u);
        epack[pos] = ((u64)(unsigned)dst << 32) | (unsigned)src;
    }
}

// ---------------- fused edge-parallel gather + MFMA GEMM ----------------

__global__ __launch_bounds__(256, 2) void fused_kernel(const __hip_bfloat16* __restrict__ xb,
                                                       const u64* __restrict__ epack,
                                                       const unsigned* __restrict__ off,
                                                       const __hip_bfloat16* __restrict__ WbT,
                                                       const float* __restrict__ bias,
                                                       float* __restrict__ out,
                                                       int n_nodes, int n_rel) {
    __shared__ __align__(16) float sAf[BR * C128];            // 32 KB, swizzled chunkf
    __shared__ __align__(16) __hip_bfloat16 sW[C128 * C128];  // 32 KB, swizzled chunk
    __shared__ unsigned soff[BR + 1];
    const int t = threadIdx.x;
    const int lane = t & 63, w = t >> 6;
    const int g = t >> 4;        // 16-lane group 0..15
    const int l16 = t & 15;
    const int row0 = blockIdx.x * BR;
    const int nrows = min(BR, n_nodes - row0);
    const unsigned short* xbu = reinterpret_cast<const unsigned short*>(xb);

    f32x4 acc[8];
#pragma unroll
    for (int i = 0; i < 8; ++i) acc[i] = (f32x4){0.f, 0.f, 0.f, 0.f};

    for (int p = 0; p < n_rel; ++p) {
        const int key0 = p * n_nodes + row0;
        // zero f32 accumulation tile + load tile's CSR offsets
        f32x4 z = (f32x4){0.f, 0.f, 0.f, 0.f};
#pragma unroll
        for (int i = 0; i < 8; ++i)
            reinterpret_cast<f32x4*>(sAf)[t + 256 * i] = z;
        if (t <= nrows) soff[t] = off[key0 + t];
        __syncthreads();

        // stage W async (overlaps edge loop)
        const char* wp = (const char*)(WbT + ((size_t)p << 14));
        char* swp = (char*)sW;
#pragma unroll
        for (int i = 0; i < 8; ++i) {
            int seg = i * 4 + w;  // 32 x 1KB segments
            gload_lds16(swp + seg * 1024 + lane * 16, wp + seg * 1024 + lane * 16);
        }

        // edge-parallel accumulate: group g strides the tile's edge range
        const unsigned ebeg = soff[0], eend = soff[nrows];
        unsigned e = ebeg + g;
        while (e + 16 < eend) {  // 2-deep for MLP
            u64 pk0 = epack[e];
            u64 pk1 = epack[e + 16];
            int s0 = (int)(unsigned)pk0, s1 = (int)(unsigned)pk1;
            ushort4v a0 = *reinterpret_cast<const ushort4v*>(xbu + ((size_t)s0 << 7) + l16 * 4);
            ushort4v b0 = *reinterpret_cast<const ushort4v*>(xbu + ((size_t)s0 << 7) + 64 + l16 * 4);
            ushort4v a1 = *reinterpret_cast<const ushort4v*>(xbu + ((size_t)s1 << 7) + l16 * 4);
            ushort4v b1 = *reinterpret_cast<const ushort4v*>(xbu + ((size_t)s1 << 7) + 64 + l16 * 4);
            int r0 = (int)(pk0 >> 32) - row0;
            int r1 = (int)(pk1 >> 32) - row0;
            int ba0 = r0 * C128 + ((l16 ^ (r0 & 7)) << 2);
            int bb0 = r0 * C128 + (((16 + l16) ^ (r0 & 7)) << 2);
            int ba1 = r1 * C128 + ((l16 ^ (r1 & 7)) << 2);
            int bb1 = r1 * C128 + (((16 + l16) ^ (r1 & 7)) << 2);
#pragma unroll
            for (int j = 0; j < 4; ++j) {
                int c = (j + l16) & 3;  // rotate offset -> spread banks
                atomicAdd(&sAf[ba0 + c], bf16_bits_to_f32(a0[c]));
                atomicAdd(&sAf[bb0 + c], bf16_bits_to_f32(b0[c]));
                atomicAdd(&sAf[ba1 + c], bf16_bits_to_f32(a1[c]));
                atomicAdd(&sAf[bb1 + c], bf16_bits_to_f32(b1[c]));
            }
            e += 32;
        }
        if (e < eend) {
            u64 pk0 = epack[e];
            int s0 = (int)(unsigned)pk0;
            ushort4v a0 = *reinterpret_cast<const ushort4v*>(xbu + ((size_t)s0 << 7) + l16 * 4);
            ushort4v b0 = *reinterpret_cast<const ushort4v*>(xbu + ((size_t)s0 << 7) + 64 + l16 * 4);
            int r0 = (int)(pk0 >> 32) - row0;
            int ba0 = r0 * C128 + ((l16 ^ (r0 & 7)) << 2);
            int bb0 = r0 * C128 + (((16 + l16) ^ (r0 & 7)) << 2);
#pragma unroll
            for (int j = 0; j < 4; ++j) {
                int c = (j + l16) & 3;
                atomicAdd(&sAf[ba0 + c], bf16_bits_to_f32(a0[c]));
                atomicAdd(&sAf[bb0 + c], bf16_bits_to_f32(b0[c]));
            }
        }
        __syncthreads();  // drains ds_adds + W gloads

        // normalize -> bf16 A-fragments in registers (fragment-ownership reads)
        const int rl = w * 16 + l16;  // row within tile
        unsigned cntv = (rl < nrows) ? (soff[rl + 1] - soff[rl]) : 0u;
        float inv = cntv ? 1.0f / (float)cntv : 0.0f;
        short8 af[4];
#pragma unroll
        for (int kt = 0; kt < 4; ++kt) {
            int cfA = (kt * 4 + (lane >> 4)) * 2;
            f32x4 u0 = *reinterpret_cast<const f32x4*>(&sAf[rl * C128 + ((cfA ^ (rl & 7)) << 2)]);
            f32x4 u1 = *reinterpret_cast<const f32x4*>(&sAf[rl * C128 + (((cfA + 1) ^ (rl & 7)) << 2)]);
            short8 o;
#pragma unroll
            for (int j = 0; j < 4; ++j)
                o[j] = (short)__bfloat16_as_ushort(__float2bfloat16(u0[j] * inv));
#pragma unroll
            for (int j = 0; j < 4; ++j)
                o[4 + j] = (short)__bfloat16_as_ushort(__float2bfloat16(u1[j] * inv));
            af[kt] = o;
        }

        // MFMA: acc[nt] += af[kt] x W-frag
#pragma unroll
        for (int kt = 0; kt < 4; ++kt) {
            int chunk = kt * 4 + (lane >> 4);
#pragma unroll
            for (int nt = 0; nt < 8; ++nt) {
                int wn = nt * 16 + l16;
                short8 bf = *reinterpret_cast<const short8*>(
                    &sW[(wn << 7) + ((chunk ^ (wn & 7)) << 3)]);
                acc[nt] = __builtin_amdgcn_mfma_f32_16x16x32_bf16(af[kt], bf, acc[nt], 0, 0, 0);
            }
        }
        __syncthreads();  // protect sAf/sW before next relation overwrites
    }

    // epilogue: D row = 4*(lane>>4)+i, col = lane&15 (per 16x16 tile)
    const int rbase = row0 + w * 16 + ((lane >> 4) << 2);
    const int cbase = l16;
#pragma unroll
    for (int nt = 0; nt < 8; ++nt) {
        int col = nt * 16 + cbase;
        float b = bias[col];
#pragma unroll
        for (int i = 0; i < 4; ++i) {
            int r = rbase + i;
            if (r < n_nodes)
                out[(size_t)r * C128 + col] = acc[nt][i] + b;
        }
    }
}

// ---------------- host ----------------

static inline char* align16p(char* p) {
    return (char*)(((uintptr_t)p + 15) & ~(uintptr_t)15);
}

extern "C" void kernel_launch(void* const* d_in, const int* in_sizes, int n_in,
                              void* d_out, int out_size, void* d_ws, size_t ws_size,
                              hipStream_t stream) {
    const float* x    = (const float*)d_in[0];
    const int*   ei   = (const int*)d_in[1];   // [2][E]
    const int*   et   = (const int*)d_in[2];   // [E]
    const float* W    = (const float*)d_in[3]; // [R][128][128]
    const float* bias = (const float*)d_in[4]; // [128]
    float* out = (float*)d_out;

    const int n_nodes = in_sizes[0] / C128;
    const int n_edges = in_sizes[2];
    const int n_rel   = in_sizes[3] / (C128 * C128);
    const int RN = n_rel * n_nodes;

    // workspace: off | cursor | part | epack(u64) | WbT | xb   (~22 MB)
    char* p = (char*)d_ws;
    unsigned* off = (unsigned*)p;      p += (size_t)(RN + 1) * 4; p = align16p(p);
    unsigned* cursor = (unsigned*)p;   p += (size_t)RN * 4;       p = align16p(p);
    unsigned* part = (unsigned*)p;     p += 4096 * 4;
    u64* epack = (u64*)p;              p += (size_t)n_edges * 8;  p = align16p(p);
    __hip_bfloat16* WbT = (__hip_bfloat16*)p; p += (size_t)n_rel * C128 * C128 * 2; p = align16p(p);
    __hip_bfloat16* xb = (__hip_bfloat16*)p;

    hipMemsetAsync(cursor, 0, (size_t)RN * 4, stream);

    // hist + wconv + xconv in one launch
    int wtot = n_rel * C128 * C128;
    int xt8 = n_nodes * (C128 / 8);
    int hblk = (n_edges + 255) / 256;
    int wblk = (wtot + 255) / 256;
    int xblk = (xt8 + 255) / 256;
    pre_kernel<<<hblk + wblk + xblk, 256, 0, stream>>>(ei, et, cursor, W, WbT, x, xb,
                                                       n_edges, n_nodes, hblk, wblk, wtot, xt8);

    int nblk = (RN + 1023) / 1024;
    scan1_kernel<<<nblk, 256, 0, stream>>>(cursor, part, RN);
    scan2_kernel<<<1, 512, 0, stream>>>(part, nblk);
    scan3_kernel<<<nblk, 256, 0, stream>>>(cursor, off, part, RN, n_edges);
    place_kernel<<<(n_edges + 255) / 256, 256, 0, stream>>>(ei, et, cursor, epack,
                                                            n_edges, n_nodes);

    int mblk = (n_nodes + BR - 1) / BR;
    fused_kernel<<<mblk, 256, 0, stream>>>(xb, epack, off, WbT, bias, out, n_nodes, n_rel);
}

// Round 6
// 335.825 us; speedup vs baseline: 1.9008x; 1.9008x over previous
//
#include <hip/hip_runtime.h>
#include <hip/hip_bf16.h>
#include <hip/hip_cooperative_groups.h>

namespace cg = cooperative_groups;

// SimpleGraphConv (RGCN-mean), fused aggregate-first, register-gather:
//   out[n] = bias + sum_r ( mean_{e: dst=n, type=r} x[src[e]] ) @ W[r]
//
//   A. ONE cooperative kernel: hist+wconv+xconv | scan1 | scan2 | scan3 | place
//      (grid.sync between phases -> kills 5 inter-dispatch gaps)
//   B. ONE fused kernel: per 64-row tile, per relation:
//      each lane gathers ITS MFMA A-fragment (row w*16+l16, chunks kt*32+cg*8)
//      in f32 registers over the row's CSR run -> no LDS A-tile, no atomics,
//      64 independent load chains per wave. W async-staged (pre-swizzled).
//      acc held across relations; out written once.

#define C128 128
#define BR 64

typedef __attribute__((ext_vector_type(8))) short short8;
typedef __attribute__((ext_vector_type(4))) float f32x4;

__device__ __forceinline__ void gload_lds16(void* lds, const void* gsrc) {
    __builtin_amdgcn_global_load_lds(
        (const __attribute__((address_space(1))) unsigned int*)gsrc,
        (__attribute__((address_space(3))) unsigned int*)lds, 16, 0, 0);
}

__device__ __forceinline__ float bf16u_f32(unsigned short u) {
    union { unsigned int i; float f; } c;
    c.i = ((unsigned int)u) << 16;
    return c.f;
}

// ---------------- cooperative sort+convert kernel ----------------
// grid = nblk blocks x 256 (nblk = ceil(RN/1024)), all co-resident.

__global__ __launch_bounds__(256) void sort_kernel(
    const int* __restrict__ ei, const int* __restrict__ et,
    unsigned* __restrict__ cursor, unsigned* __restrict__ off,
    unsigned* __restrict__ part, int* __restrict__ sorted_src,
    const float* __restrict__ W, __hip_bfloat16* __restrict__ WbT,
    const float* __restrict__ x, __hip_bfloat16* __restrict__ xb,
    int n_edges, int n_nodes, int RN, int wtot, int xt8) {
    cg::grid_group grid = cg::this_grid();
    const int t = threadIdx.x;
    const int bid = blockIdx.x;
    const int gsz = gridDim.x * 256;
    const int gtid = bid * 256 + t;
    __shared__ unsigned s[256];

    // P0: hist + weight convert (bf16, transposed, XOR-swizzled) + x convert
    for (int e = gtid; e < n_edges; e += gsz)
        atomicAdd(&cursor[(size_t)et[e] * n_nodes + ei[n_edges + e]], 1u);
    for (int i = gtid; i < wtot; i += gsz) {
        int r = i >> 14, k = (i >> 7) & 127, n = i & 127;
        WbT[(r << 14) + (n << 7) + ((((k >> 3) ^ (n & 7)) << 3) | (k & 7))] =
            __float2bfloat16(W[i]);
    }
    for (int i = gtid; i < xt8; i += gsz) {
        const float4* src = reinterpret_cast<const float4*>(x + (size_t)i * 8);
        float4 v0 = src[0], v1 = src[1];
        short8 o;
        o[0] = (short)__bfloat16_as_ushort(__float2bfloat16(v0.x));
        o[1] = (short)__bfloat16_as_ushort(__float2bfloat16(v0.y));
        o[2] = (short)__bfloat16_as_ushort(__float2bfloat16(v0.z));
        o[3] = (short)__bfloat16_as_ushort(__float2bfloat16(v0.w));
        o[4] = (short)__bfloat16_as_ushort(__float2bfloat16(v1.x));
        o[5] = (short)__bfloat16_as_ushort(__float2bfloat16(v1.y));
        o[6] = (short)__bfloat16_as_ushort(__float2bfloat16(v1.z));
        o[7] = (short)__bfloat16_as_ushort(__float2bfloat16(v1.w));
        *reinterpret_cast<short8*>(reinterpret_cast<unsigned short*>(xb) + (size_t)i * 8) = o;
    }
    grid.sync();

    // P1: block-level partial sums of cursor (1024 keys per block)
    {
        int base = bid * 1024 + t * 4;
        unsigned sum = 0;
#pragma unroll
        for (int i = 0; i < 4; ++i) {
            int idx = base + i;
            if (idx < RN) sum += cursor[idx];
        }
        s[t] = sum;
        __syncthreads();
        for (int d = 128; d > 0; d >>= 1) {
            if (t < d) s[t] += s[t + d];
            __syncthreads();
        }
        if (t == 0) part[bid] = s[0];
    }
    grid.sync();

    // P2: block 0 exclusive-scans part[]
    if (bid == 0) {
        int nb = gridDim.x;
        unsigned run = 0;
        for (int base = 0; base < nb; base += 256) {
            int i = base + t;
            unsigned v = (i < nb) ? part[i] : 0u;
            s[t] = v;
            __syncthreads();
            for (int d = 1; d < 256; d <<= 1) {
                unsigned u = (t >= d) ? s[t - d] : 0u;
                __syncthreads();
                s[t] += u;
                __syncthreads();
            }
            if (i < nb) part[i] = run + s[t] - v;
            unsigned tot = s[255];
            __syncthreads();
            run += tot;
        }
    }
    grid.sync();

    // P3: per-block exclusive scan -> off, cursor (= run cursors for place)
    {
        int base = bid * 1024 + t * 4;
        unsigned v[4];
        unsigned tsum = 0;
#pragma unroll
        for (int i = 0; i < 4; ++i) {
            int idx = base + i;
            v[i] = (idx < RN) ? cursor[idx] : 0u;
            tsum += v[i];
        }
        s[t] = tsum;
        __syncthreads();
        for (int d = 1; d < 256; d <<= 1) {
            unsigned u = (t >= d) ? s[t - d] : 0u;
            __syncthreads();
            s[t] += u;
            __syncthreads();
        }
        unsigned run = s[t] - tsum + part[bid];
#pragma unroll
        for (int i = 0; i < 4; ++i) {
            int idx = base + i;
            if (idx < RN) {
                off[idx] = run;
                cursor[idx] = run;
                run += v[i];
            }
        }
        if (bid == 0 && t == 0) off[RN] = (unsigned)n_edges;
    }
    grid.sync();

    // P4: place edge srcs into CSR order
    for (int e = gtid; e < n_edges; e += gsz) {
        int src = ei[e];
        int dst = ei[n_edges + e];
        int key = et[e] * n_nodes + dst;
        unsigned pos = atomicAdd(&cursor[key], 1u);
        sorted_src[pos] = src;
    }
}

// ---------------- fused register-gather + MFMA GEMM ----------------

__global__ __launch_bounds__(256, 4) void fused_kernel(
    const __hip_bfloat16* __restrict__ xb, const int* __restrict__ ss,
    const unsigned* __restrict__ off, const __hip_bfloat16* __restrict__ WbT,
    const float* __restrict__ bias, float* __restrict__ out,
    int n_nodes, int n_rel) {
    __shared__ __align__(16) __hip_bfloat16 sW[C128 * C128];  // 32 KB, swizzled
    const int t = threadIdx.x, lane = t & 63, w = t >> 6;
    const int l16 = lane & 15, cg = lane >> 4;
    const int row0 = blockIdx.x * BR;
    const int rl = w * 16 + l16;   // tile row owned by this lane
    const int node = row0 + rl;
    const unsigned short* xbu = reinterpret_cast<const unsigned short*>(xb);

    f32x4 acc[8];
#pragma unroll
    for (int i = 0; i < 8; ++i) acc[i] = (f32x4){0.f, 0.f, 0.f, 0.f};

    for (int p = 0; p < n_rel; ++p) {
        // CSR run for this lane's (rel,row) — start the chain early
        unsigned beg = 0, end = 0;
        if (node < n_nodes) {
            size_t key = (size_t)p * n_nodes + node;
            beg = off[key];
            end = off[key + 1];
        }
        // async W staging (overlaps the gather loop)
        const char* wp = (const char*)(WbT + ((size_t)p << 14));
#pragma unroll
        for (int i = 0; i < 8; ++i) {
            int seg = i * 4 + w;  // 32 x 1KB segments
            gload_lds16((char*)sW + seg * 1024 + lane * 16, wp + seg * 1024 + lane * 16);
        }
        // register gather: lane accumulates its 4x8 A-fragment elements
        float a[4][8];
#pragma unroll
        for (int kt = 0; kt < 4; ++kt)
#pragma unroll
            for (int j = 0; j < 8; ++j) a[kt][j] = 0.f;
        int n = (int)(end - beg);
        int e = (int)beg;
        int snx = (n > 0) ? ss[e] : 0;  // src prefetch breaks the chain
        for (int i = 0; i < n; ++i) {
            int sv = snx;
            snx = (i + 1 < n) ? ss[e + i + 1] : 0;
            const unsigned short* rowp = xbu + ((size_t)sv << 7) + cg * 8;
            short8 v0 = *reinterpret_cast<const short8*>(rowp);
            short8 v1 = *reinterpret_cast<const short8*>(rowp + 32);
            short8 v2 = *reinterpret_cast<const short8*>(rowp + 64);
            short8 v3 = *reinterpret_cast<const short8*>(rowp + 96);
#pragma unroll
            for (int j = 0; j < 8; ++j) {
                a[0][j] += bf16u_f32((unsigned short)v0[j]);
                a[1][j] += bf16u_f32((unsigned short)v1[j]);
                a[2][j] += bf16u_f32((unsigned short)v2[j]);
                a[3][j] += bf16u_f32((unsigned short)v3[j]);
            }
        }
        float inv = (n > 0) ? 1.0f / (float)n : 0.0f;
        short8 af[4];
#pragma unroll
        for (int kt = 0; kt < 4; ++kt) {
            short8 o;
#pragma unroll
            for (int j = 0; j < 8; ++j)
                o[j] = (short)__bfloat16_as_ushort(__float2bfloat16(a[kt][j] * inv));
            af[kt] = o;
        }
        __syncthreads();  // drains W gload (vmcnt) — sW ready

        // MFMA: acc[nt] += af[kt] x W-frag(nt,kt)
#pragma unroll
        for (int kt = 0; kt < 4; ++kt) {
            int chunk = kt * 4 + cg;
#pragma unroll
            for (int nt = 0; nt < 8; ++nt) {
                int wn = nt * 16 + l16;
                short8 bf = *reinterpret_cast<const short8*>(
                    &sW[(wn << 7) + ((chunk ^ (wn & 7)) << 3)]);
                acc[nt] = __builtin_amdgcn_mfma_f32_16x16x32_bf16(af[kt], bf, acc[nt], 0, 0, 0);
            }
        }
        __syncthreads();  // protect sW before next relation restages
    }

    // epilogue: D row = 4*(lane>>4)+i, col = lane&15 (per 16x16 tile)
    const int rbase = row0 + w * 16 + (cg << 2);
#pragma unroll
    for (int nt = 0; nt < 8; ++nt) {
        int col = nt * 16 + l16;
        float b = bias[col];
#pragma unroll
        for (int i = 0; i < 4; ++i) {
            int r = rbase + i;
            if (r < n_nodes)
                out[(size_t)r * C128 + col] = acc[nt][i] + b;
        }
    }
}

// ---------------- host ----------------

static inline char* align16p(char* p) {
    return (char*)(((uintptr_t)p + 15) & ~(uintptr_t)15);
}

extern "C" void kernel_launch(void* const* d_in, const int* in_sizes, int n_in,
                              void* d_out, int out_size, void* d_ws, size_t ws_size,
                              hipStream_t stream) {
    const float* x    = (const float*)d_in[0];
    const int*   ei   = (const int*)d_in[1];   // [2][E]
    const int*   et   = (const int*)d_in[2];   // [E]
    const float* W    = (const float*)d_in[3]; // [R][128][128]
    const float* bias = (const float*)d_in[4]; // [128]
    float* out = (float*)d_out;

    const int n_nodes = in_sizes[0] / C128;
    const int n_edges = in_sizes[2];
    const int n_rel   = in_sizes[3] / (C128 * C128);
    int RN = n_rel * n_nodes;

    // workspace: off | cursor | part | sorted_src | WbT | xb   (~19 MB)
    char* p = (char*)d_ws;
    unsigned* off = (unsigned*)p;      p += (size_t)(RN + 1) * 4; p = align16p(p);
    unsigned* cursor = (unsigned*)p;   p += (size_t)RN * 4;       p = align16p(p);
    unsigned* part = (unsigned*)p;     p += 4096 * 4;
    int* sorted_src = (int*)p;         p += (size_t)n_edges * 4;  p = align16p(p);
    __hip_bfloat16* WbT = (__hip_bfloat16*)p; p += (size_t)n_rel * C128 * C128 * 2; p = align16p(p);
    __hip_bfloat16* xb = (__hip_bfloat16*)p;

    hipMemsetAsync(cursor, 0, (size_t)RN * 4, stream);

    int wtot = n_rel * C128 * C128;
    int xt8 = n_nodes * (C128 / 8);
    int nblk = (RN + 1023) / 1024;  // 391 blocks — all co-resident (<< 2048 cap)

    const int* ei_a = ei;
    const int* et_a = et;
    const float* W_a = W;
    const float* x_a = x;
    void* args[] = {
        (void*)&ei_a, (void*)&et_a, (void*)&cursor, (void*)&off, (void*)&part,
        (void*)&sorted_src, (void*)&W_a, (void*)&WbT, (void*)&x_a, (void*)&xb,
        (void*)&n_edges, (void*)&n_nodes, (void*)&RN, (void*)&wtot, (void*)&xt8};
    hipLaunchCooperativeKernel((void*)sort_kernel, dim3(nblk), dim3(256), args, 0, stream);

    int mblk = (n_nodes + BR - 1) / BR;
    fused_kernel<<<mblk, 256, 0, stream>>>(xb, sorted_src, off, WbT, bias, out,
                                           n_nodes, n_rel);
}

// Round 7
// 146.757 us; speedup vs baseline: 4.3496x; 2.2883x over previous
//
#include <hip/hip_runtime.h>
#include <hip/hip_bf16.h>

// SimpleGraphConv (RGCN-mean), fused aggregate-first, register-gather:
//   out[n] = bias + sum_r ( mean_{e: dst=n, type=r} x[src[e]] ) @ W[r]
//
//   1. split counting-sort pipeline (each phase right-sized grid):
//      pre(hist+wconv+xconv) -> scan1 -> scan2 -> scan3 -> place
//   2. ONE fused kernel: per 64-row tile, per relation:
//      each lane gathers ITS MFMA A-fragment (row w*16+l16, chunks cg+{0,4,8,12})
//      in f32 registers over the row's CSR run -> no LDS A-tile, no atomics,
//      64 independent load chains per wave. W async-staged (pre-swizzled).
//      acc held across relations; out written once.

#define C128 128
#define BR 64

typedef __attribute__((ext_vector_type(8))) short short8;
typedef __attribute__((ext_vector_type(4))) float f32x4;

__device__ __forceinline__ void gload_lds16(void* lds, const void* gsrc) {
    __builtin_amdgcn_global_load_lds(
        (const __attribute__((address_space(1))) unsigned int*)gsrc,
        (__attribute__((address_space(3))) unsigned int*)lds, 16, 0, 0);
}

__device__ __forceinline__ float bf16u_f32(unsigned short u) {
    union { unsigned int i; float f; } c;
    c.i = ((unsigned int)u) << 16;
    return c.f;
}

// ------- merged: hist | wconv | xconv (independent work, block-split) -------

__global__ __launch_bounds__(256) void pre_kernel(const int* __restrict__ ei,
                                                  const int* __restrict__ et,
                                                  unsigned* __restrict__ cursor,
                                                  const float* __restrict__ W,
                                                  __hip_bfloat16* __restrict__ WbT,
                                                  const float* __restrict__ x,
                                                  __hip_bfloat16* __restrict__ xb,
                                                  int n_edges, int n_nodes,
                                                  int hblk, int wblk, int wtot, int xt8) {
    int bid = blockIdx.x;
    if (bid < hblk) {
        int e = bid * 256 + threadIdx.x;
        if (e < n_edges)
            atomicAdd(&cursor[(size_t)et[e] * n_nodes + ei[n_edges + e]], 1u);
    } else if (bid < hblk + wblk) {
        int i = (bid - hblk) * 256 + threadIdx.x;
        if (i < wtot) {
            int r = i >> 14, k = (i >> 7) & 127, n = i & 127;
            WbT[(r << 14) + (n << 7) + ((((k >> 3) ^ (n & 7)) << 3) | (k & 7))] =
                __float2bfloat16(W[i]);
        }
    } else {
        int i = (bid - hblk - wblk) * 256 + threadIdx.x;
        if (i < xt8) {
            const float4* src = reinterpret_cast<const float4*>(x + (size_t)i * 8);
            float4 v0 = src[0], v1 = src[1];
            short8 o;
            o[0] = (short)__bfloat16_as_ushort(__float2bfloat16(v0.x));
            o[1] = (short)__bfloat16_as_ushort(__float2bfloat16(v0.y));
            o[2] = (short)__bfloat16_as_ushort(__float2bfloat16(v0.z));
            o[3] = (short)__bfloat16_as_ushort(__float2bfloat16(v0.w));
            o[4] = (short)__bfloat16_as_ushort(__float2bfloat16(v1.x));
            o[5] = (short)__bfloat16_as_ushort(__float2bfloat16(v1.y));
            o[6] = (short)__bfloat16_as_ushort(__float2bfloat16(v1.z));
            o[7] = (short)__bfloat16_as_ushort(__float2bfloat16(v1.w));
            *reinterpret_cast<short8*>(reinterpret_cast<unsigned short*>(xb) + (size_t)i * 8) = o;
        }
    }
}

// ---------------- scan (3-kernel) ----------------

__global__ __launch_bounds__(256) void scan1_kernel(const unsigned* __restrict__ cnt,
                                                    unsigned* __restrict__ part, int total) {
    __shared__ unsigned s[256];
    int t = threadIdx.x;
    int base = blockIdx.x * 1024 + t * 4;
    unsigned sum = 0;
#pragma unroll
    for (int i = 0; i < 4; ++i) {
        int idx = base + i;
        if (idx < total) sum += cnt[idx];
    }
    s[t] = sum;
    __syncthreads();
    for (int d = 128; d > 0; d >>= 1) {
        if (t < d) s[t] += s[t + d];
        __syncthreads();
    }
    if (t == 0) part[blockIdx.x] = s[0];
}

__global__ __launch_bounds__(512) void scan2_kernel(unsigned* __restrict__ part, int nblk) {
    __shared__ unsigned s[512];
    int t = threadIdx.x;
    unsigned run = 0;
    for (int base = 0; base < nblk; base += 512) {
        int i = base + t;
        unsigned v = (i < nblk) ? part[i] : 0u;
        s[t] = v;
        __syncthreads();
        for (int d = 1; d < 512; d <<= 1) {
            unsigned u = (t >= d) ? s[t - d] : 0u;
            __syncthreads();
            s[t] += u;
            __syncthreads();
        }
        unsigned incl = s[t];
        if (i < nblk) part[i] = run + incl - v;  // exclusive
        unsigned tot = s[511];
        __syncthreads();
        run += tot;
    }
}

__global__ __launch_bounds__(256) void scan3_kernel(unsigned* __restrict__ cursor,
                                                    unsigned* __restrict__ off,
                                                    const unsigned* __restrict__ part,
                                                    int total, int n_edges) {
    __shared__ unsigned s[256];
    int t = threadIdx.x;
    int base = blockIdx.x * 1024 + t * 4;
    unsigned v[4];
    unsigned tsum = 0;
#pragma unroll
    for (int i = 0; i < 4; ++i) {
        int idx = base + i;
        v[i] = (idx < total) ? cursor[idx] : 0u;
        tsum += v[i];
    }
    s[t] = tsum;
    __syncthreads();
    for (int d = 1; d < 256; d <<= 1) {
        unsigned u = (t >= d) ? s[t - d] : 0u;
        __syncthreads();
        s[t] += u;
        __syncthreads();
    }
    unsigned run = s[t] - tsum + part[blockIdx.x];
#pragma unroll
    for (int i = 0; i < 4; ++i) {
        int idx = base + i;
        if (idx < total) {
            off[idx] = run;
            cursor[idx] = run;
            run += v[i];
        }
    }
    if (blockIdx.x == 0 && t == 0) off[total] = (unsigned)n_edges;
}

__global__ __launch_bounds__(256) void place_kernel(const int* __restrict__ ei,
                                                    const int* __restrict__ et,
                                                    unsigned* __restrict__ cursor,
                                                    int* __restrict__ sorted_src,
                                                    int n_edges, int n_nodes) {
    int e = blockIdx.x * 256 + threadIdx.x;
    if (e < n_edges) {
        int src = ei[e];
        int dst = ei[n_edges + e];
        int key = et[e] * n_nodes + dst;
        unsigned pos = atomicAdd(&cursor[key], 1u);
        sorted_src[pos] = src;
    }
}

// ---------------- fused register-gather + MFMA GEMM ----------------

__global__ __launch_bounds__(256, 4) void fused_kernel(
    const __hip_bfloat16* __restrict__ xb, const int* __restrict__ ss,
    const unsigned* __restrict__ off, const __hip_bfloat16* __restrict__ WbT,
    const float* __restrict__ bias, float* __restrict__ out,
    int n_nodes, int n_rel) {
    __shared__ __align__(16) __hip_bfloat16 sW[C128 * C128];  // 32 KB, swizzled
    const int t = threadIdx.x, lane = t & 63, w = t >> 6;
    const int l16 = lane & 15, cg = lane >> 4;
    const int row0 = blockIdx.x * BR;
    const int rl = w * 16 + l16;   // tile row owned by this lane (4 cg-lanes/row)
    const int node = row0 + rl;
    const unsigned short* xbu = reinterpret_cast<const unsigned short*>(xb);

    f32x4 acc[8];
#pragma unroll
    for (int i = 0; i < 8; ++i) acc[i] = (f32x4){0.f, 0.f, 0.f, 0.f};

    for (int p = 0; p < n_rel; ++p) {
        // CSR run for this lane's (rel,row) — start the chain early
        unsigned beg = 0, end = 0;
        if (node < n_nodes) {
            size_t key = (size_t)p * n_nodes + node;
            beg = off[key];
            end = off[key + 1];
        }
        // async W staging (overlaps the gather loop)
        const char* wp = (const char*)(WbT + ((size_t)p << 14));
#pragma unroll
        for (int i = 0; i < 8; ++i) {
            int seg = i * 4 + w;  // 32 x 1KB segments
            gload_lds16((char*)sW + seg * 1024 + lane * 16, wp + seg * 1024 + lane * 16);
        }
        // register gather: lane accumulates its 4x8 A-fragment elements
        float a[4][8];
#pragma unroll
        for (int kt = 0; kt < 4; ++kt)
#pragma unroll
            for (int j = 0; j < 8; ++j) a[kt][j] = 0.f;
        int n = (int)(end - beg);
        int e = (int)beg;
        int snx = (n > 0) ? ss[e] : 0;  // src prefetch breaks the chain
        for (int i = 0; i < n; ++i) {
            int sv = snx;
            snx = (i + 1 < n) ? ss[e + i + 1] : 0;
            const unsigned short* rowp = xbu + ((size_t)sv << 7) + cg * 8;
            short8 v0 = *reinterpret_cast<const short8*>(rowp);
            short8 v1 = *reinterpret_cast<const short8*>(rowp + 32);
            short8 v2 = *reinterpret_cast<const short8*>(rowp + 64);
            short8 v3 = *reinterpret_cast<const short8*>(rowp + 96);
#pragma unroll
            for (int j = 0; j < 8; ++j) {
                a[0][j] += bf16u_f32((unsigned short)v0[j]);
                a[1][j] += bf16u_f32((unsigned short)v1[j]);
                a[2][j] += bf16u_f32((unsigned short)v2[j]);
                a[3][j] += bf16u_f32((unsigned short)v3[j]);
            }
        }
        float inv = (n > 0) ? 1.0f / (float)n : 0.0f;
        short8 af[4];
#pragma unroll
        for (int kt = 0; kt < 4; ++kt) {
            short8 o;
#pragma unroll
            for (int j = 0; j < 8; ++j)
                o[j] = (short)__bfloat16_as_ushort(__float2bfloat16(a[kt][j] * inv));
            af[kt] = o;
        }
        __syncthreads();  // drains W gload (vmcnt) — sW ready

        // MFMA: acc[nt] += af[kt] x W-frag(nt,kt)
#pragma unroll
        for (int kt = 0; kt < 4; ++kt) {
            int chunk = kt * 4 + cg;
#pragma unroll
            for (int nt = 0; nt < 8; ++nt) {
                int wn = nt * 16 + l16;
                short8 bf = *reinterpret_cast<const short8*>(
                    &sW[(wn << 7) + ((chunk ^ (wn & 7)) << 3)]);
                acc[nt] = __builtin_amdgcn_mfma_f32_16x16x32_bf16(af[kt], bf, acc[nt], 0, 0, 0);
            }
        }
        __syncthreads();  // protect sW before next relation restages
    }

    // epilogue: D row = 4*(lane>>4)+i, col = lane&15 (per 16x16 tile)
    const int rbase = row0 + w * 16 + (cg << 2);
#pragma unroll
    for (int nt = 0; nt < 8; ++nt) {
        int col = nt * 16 + l16;
        float b = bias[col];
#pragma unroll
        for (int i = 0; i < 4; ++i) {
            int r = rbase + i;
            if (r < n_nodes)
                out[(size_t)r * C128 + col] = acc[nt][i] + b;
        }
    }
}

// ---------------- host ----------------

static inline char* align16p(char* p) {
    return (char*)(((uintptr_t)p + 15) & ~(uintptr_t)15);
}

extern "C" void kernel_launch(void* const* d_in, const int* in_sizes, int n_in,
                              void* d_out, int out_size, void* d_ws, size_t ws_size,
                              hipStream_t stream) {
    const float* x    = (const float*)d_in[0];
    const int*   ei   = (const int*)d_in[1];   // [2][E]
    const int*   et   = (const int*)d_in[2];   // [E]
    const float* W    = (const float*)d_in[3]; // [R][128][128]
    const float* bias = (const float*)d_in[4]; // [128]
    float* out = (float*)d_out;

    const int n_nodes = in_sizes[0] / C128;
    const int n_edges = in_sizes[2];
    const int n_rel   = in_sizes[3] / (C128 * C128);
    const int RN = n_rel * n_nodes;

    // workspace: off | cursor | part | sorted_src | WbT | xb   (~19 MB)
    char* p = (char*)d_ws;
    unsigned* off = (unsigned*)p;      p += (size_t)(RN + 1) * 4; p = align16p(p);
    unsigned* cursor = (unsigned*)p;   p += (size_t)RN * 4;       p = align16p(p);
    unsigned* part = (unsigned*)p;     p += 4096 * 4;
    int* sorted_src = (int*)p;         p += (size_t)n_edges * 4;  p = align16p(p);
    __hip_bfloat16* WbT = (__hip_bfloat16*)p; p += (size_t)n_rel * C128 * C128 * 2; p = align16p(p);
    __hip_bfloat16* xb = (__hip_bfloat16*)p;

    hipMemsetAsync(cursor, 0, (size_t)RN * 4, stream);

    // hist + wconv + xconv in one launch (right-sized grid, block-range split)
    int wtot = n_rel * C128 * C128;
    int xt8 = n_nodes * (C128 / 8);
    int hblk = (n_edges + 255) / 256;
    int wblk = (wtot + 255) / 256;
    int xblk = (xt8 + 255) / 256;
    pre_kernel<<<hblk + wblk + xblk, 256, 0, stream>>>(ei, et, cursor, W, WbT, x, xb,
                                                       n_edges, n_nodes, hblk, wblk, wtot, xt8);

    int nblk = (RN + 1023) / 1024;
    scan1_kernel<<<nblk, 256, 0, stream>>>(cursor, part, RN);
    scan2_kernel<<<1, 512, 0, stream>>>(part, nblk);
    scan3_kernel<<<nblk, 256, 0, stream>>>(cursor, off, part, RN, n_edges);
    place_kernel<<<(n_edges + 255) / 256, 256, 0, stream>>>(ei, et, cursor, sorted_src,
                                                            n_edges, n_nodes);

    int mblk = (n_nodes + BR - 1) / BR;
    fused_kernel<<<mblk, 256, 0, stream>>>(xb, sorted_src, off, WbT, bias, out,
                                           n_nodes, n_rel);
}